// Round 3
// baseline (649.326 us; speedup 1.0000x reference)
//
#include <hip/hip_runtime.h>
#include <math.h>

#define NQ_   32
#define M_    32
#define ND_   200
#define N_    160
#define H_    768
#define DIM_  128
#define DROWS_ (ND_ * N_)          // 32000
#define QROWS_ (NQ_ * M_)          // 1024
#define TROWS_ (DROWS_ + QROWS_)   // 33024

// async global->LDS, 16B per lane: LDS dest = wave-uniform base + lane*16
__device__ __forceinline__ void gl_lds16(const float* g, float* l) {
    __builtin_amdgcn_global_load_lds(
        (const __attribute__((address_space(1))) unsigned int*)g,
        (__attribute__((address_space(3))) unsigned int*)l, 16, 0, 0);
}

#define ASM_VMCNT(n) asm volatile("s_waitcnt vmcnt(" #n ")" ::: "memory")
#define ASM_LGKM0    asm volatile("s_waitcnt lgkmcnt(0)" ::: "memory")

// ---------------------------------------------------------------------------
// Merged projection, 2-chunk-ahead counted-vmcnt pipeline.
// Rows 0..31999 = D, 32000..33023 = Q. Tile 32 rows x 128 cols, 128 threads
// (2 waves), per-thread 4x8, K-chunk 16.
//   - W chunk staged via global_load_lds into a 3-deep ring Ws[c%3]; X chunk
//     reg-staged into rotating xr0/xr1 (loop unrolled x2 -> static regs).
//   - Loads for chunk c+2 are issued at chunk c -> each chunk's loads have
//     TWO compute phases (~2048 cy) to cover ~900 cy HBM latency.
//   - Raw s_barrier + per-wave s_waitcnt vmcnt(5) (chunk c's 5 vmem ops done,
//     chunk c+1's 5 still in flight; vmcnt retires in issue order) +
//     lgkmcnt(0) for the Xt ds_writes.
//     Race audit: buffer (c+2)%3 is rewritten only after the barrier that
//     proves every wave finished computing chunk c-1 = same buffer. Each
//     wave's vmcnt(5) covers its own half of the buffer; the barrier after
//     it publishes the other wave's half.
// Epilogue: cross-row float4 stores. FMA order bit-identical to prior rounds.
// ---------------------------------------------------------------------------
__global__ __launch_bounds__(128) void proj_kernel(
    const float* __restrict__ Dmat, const float* __restrict__ Qmat,
    const float* __restrict__ W, float* __restrict__ DpT,
    float* __restrict__ QpT)
{
    __shared__ __align__(16) float Xt[2][16][32];    // 4 KB
    __shared__ __align__(16) float Ws[3][16][128];   // 24 KB
    const int tid  = threadIdx.x;
    const int lane = tid & 63;
    const int wv   = tid >> 6;
    const int rb   = blockIdx.x * 32;
    const int cg   = tid & 15;       // col group: cols cg*8..+7
    const int rg   = tid >> 4;       // row group 0..7: rows rg*4..+3
    const int xrow = tid >> 2;       // staging row 0..31
    const int xc4  = tid & 3;        // staging k-quad

    const int rX = rb + xrow;
    const float* xr_ptr = (rX < DROWS_) ? (Dmat + (size_t)rX * H_)
                                        : (Qmat + (size_t)(rX - DROWS_) * H_);

    float acc[4][8];
#pragma unroll
    for (int i = 0; i < 4; ++i)
#pragma unroll
        for (int j = 0; j < 8; ++j) acc[i][j] = 0.0f;

    // prologue: issue chunks 0 and 1 (5 vmem ops each per wave)
#pragma unroll
    for (int t = 0; t < 4; ++t) {
        const int part = wv * 4 + t;
        gl_lds16(W + part * 256 + lane * 4, &Ws[0][0][0] + part * 256);
    }
    float4 xr0 = *reinterpret_cast<const float4*>(xr_ptr + 0 + xc4 * 4);
#pragma unroll
    for (int t = 0; t < 4; ++t) {
        const int part = wv * 4 + t;
        gl_lds16(W + 16 * DIM_ + part * 256 + lane * 4, &Ws[1][0][0] + part * 256);
    }
    float4 xr1 = *reinterpret_cast<const float4*>(xr_ptr + 16 + xc4 * 4);

    int b0 = 0;   // (c % 3) for the even chunk of each pair
    for (int c = 0; c < 48; c += 2) {
        // ---- even chunk c: Xt[0], Ws[b0]
        {
            Xt[0][xc4*4+0][xrow] = xr0.x;   // compiler auto-waits xr0's vmcnt
            Xt[0][xc4*4+1][xrow] = xr0.y;
            Xt[0][xc4*4+2][xrow] = xr0.z;
            Xt[0][xc4*4+3][xrow] = xr0.w;
            ASM_VMCNT(5);                   // chunk c's gl_lds done (own wave)
            ASM_LGKM0;                      // Xt writes visible
            __builtin_amdgcn_s_barrier();
            if (c + 2 < 48) {
                const int kc = (c + 2) * 16;
                const int b2 = (b0 + 2 >= 3) ? b0 - 1 : b0 + 2;
                float* wdst = &Ws[0][0][0] + b2 * 2048;
                const float* wsrc = W + (size_t)kc * DIM_;
#pragma unroll
                for (int t = 0; t < 4; ++t) {
                    const int part = wv * 4 + t;
                    gl_lds16(wsrc + part * 256 + lane * 4, wdst + part * 256);
                }
                xr0 = *reinterpret_cast<const float4*>(xr_ptr + kc + xc4 * 4);
            }
            __builtin_amdgcn_sched_barrier(0);
            const float* wb = &Ws[0][0][0] + b0 * 2048;
#pragma unroll
            for (int k = 0; k < 16; ++k) {
                float a[4], b[8];
                *reinterpret_cast<float4*>(&a[0]) = *reinterpret_cast<const float4*>(&Xt[0][k][rg*4]);
                *reinterpret_cast<float4*>(&b[0]) = *reinterpret_cast<const float4*>(wb + k*128 + cg*8);
                *reinterpret_cast<float4*>(&b[4]) = *reinterpret_cast<const float4*>(wb + k*128 + cg*8 + 4);
#pragma unroll
                for (int i = 0; i < 4; ++i)
#pragma unroll
                    for (int j = 0; j < 8; ++j)
                        acc[i][j] = fmaf(a[i], b[j], acc[i][j]);
            }
        }
        // ---- odd chunk c+1: Xt[1], Ws[(b0+1)%3]
        {
            const int b1 = (b0 + 1 >= 3) ? b0 - 2 : b0 + 1;
            Xt[1][xc4*4+0][xrow] = xr1.x;   // compiler auto-waits xr1's vmcnt
            Xt[1][xc4*4+1][xrow] = xr1.y;
            Xt[1][xc4*4+2][xrow] = xr1.z;
            Xt[1][xc4*4+3][xrow] = xr1.w;
            ASM_VMCNT(5);
            ASM_LGKM0;
            __builtin_amdgcn_s_barrier();
            if (c + 3 < 48) {
                const int kc = (c + 3) * 16;
                float* wdst = &Ws[0][0][0] + b0 * 2048;   // (c+3)%3 == c%3
                const float* wsrc = W + (size_t)kc * DIM_;
#pragma unroll
                for (int t = 0; t < 4; ++t) {
                    const int part = wv * 4 + t;
                    gl_lds16(wsrc + part * 256 + lane * 4, wdst + part * 256);
                }
                xr1 = *reinterpret_cast<const float4*>(xr_ptr + kc + xc4 * 4);
            }
            __builtin_amdgcn_sched_barrier(0);
            const float* wb = &Ws[0][0][0] + b1 * 2048;
#pragma unroll
            for (int k = 0; k < 16; ++k) {
                float a[4], b[8];
                *reinterpret_cast<float4*>(&a[0]) = *reinterpret_cast<const float4*>(&Xt[1][k][rg*4]);
                *reinterpret_cast<float4*>(&b[0]) = *reinterpret_cast<const float4*>(wb + k*128 + cg*8);
                *reinterpret_cast<float4*>(&b[4]) = *reinterpret_cast<const float4*>(wb + k*128 + cg*8 + 4);
#pragma unroll
                for (int i = 0; i < 4; ++i)
#pragma unroll
                    for (int j = 0; j < 8; ++j)
                        acc[i][j] = fmaf(a[i], b[j], acc[i][j]);
            }
            b0 = (b0 + 2 >= 3) ? b0 - 1 : b0 + 2;
        }
    }

    // L2 norms: row r's 128 cols live in the 16 same-rg lanes. Same order.
    float nrm[4];
#pragma unroll
    for (int i = 0; i < 4; ++i) {
        float ss = 0.0f;
#pragma unroll
        for (int j = 0; j < 8; ++j) ss = __fadd_rn(ss, __fmul_rn(acc[i][j], acc[i][j]));
        ss = __fadd_rn(ss, __shfl_xor(ss, 1));
        ss = __fadd_rn(ss, __shfl_xor(ss, 2));
        ss = __fadd_rn(ss, __shfl_xor(ss, 4));
        ss = __fadd_rn(ss, __shfl_xor(ss, 8));
        nrm[i] = fmaxf(sqrtf(ss), 1e-12f);
    }

    if (rb < DROWS_) {
        const int dd = rb / 160, n0 = rb - dd * 160;   // 32-row blocks stay within one d
        float* o = DpT + (size_t)dd * (DIM_ * N_) + n0 + rg * 4;
#pragma unroll
        for (int j = 0; j < 8; ++j) {
            float4 v;
            v.x = acc[0][j] / nrm[0];
            v.y = acc[1][j] / nrm[1];
            v.z = acc[2][j] / nrm[2];
            v.w = acc[3][j] / nrm[3];
            *reinterpret_cast<float4*>(o + (size_t)(cg*8 + j) * N_) = v;
        }
    } else {
        const int rq = rb - DROWS_;
        const int qq = rq >> 5;
        float* o = QpT + (size_t)qq * (DIM_ * M_) + rg * 4;
#pragma unroll
        for (int j = 0; j < 8; ++j) {
            float4 v;
            v.x = acc[0][j] / nrm[0];
            v.y = acc[1][j] / nrm[1];
            v.z = acc[2][j] / nrm[2];
            v.w = acc[3][j] / nrm[3];
            *reinterpret_cast<float4*>(o + (size_t)(cg*8 + j) * M_) = v;
        }
    }
}

// ---------------------------------------------------------------------------
// Score: ONE wave per (q,d), grid 6400. Single-wave block => NO barriers:
// gl_lds completion is tracked by the issuing wave's own vmcnt. 3-buffer LDS
// ring (18.4 KB -> 8 blocks/CU), per-chunk s_waitcnt vmcnt(6): chunk c+1's 6
// loads stay in flight across the wait -> every chunk's loads get ~2 compute
// phases of latency cover. gumbel rows 0-1 + dmask + qmask issued at kernel
// start (oldest vmem ops; vmcnt retires in order, so in-loop vmcnt(6)
// implies they retired). Epilogue refills gumbel 2 rows ahead (unroll makes
// g[i&1] a static index). All per-element arithmetic, reduce orders, and
// tie-breaks bit-identical to the round-0 198 us version.
// ---------------------------------------------------------------------------
__global__ __launch_bounds__(64) void score_kernel(
    const float* __restrict__ QpT, const float* __restrict__ DpT,
    const float* __restrict__ qmask, const float* __restrict__ dmask,
    const float* __restrict__ gum, float* __restrict__ out)
{
    __shared__ __align__(16) float Qt[3][8][32];     // 3 KB
    __shared__ __align__(16) float Dt[3][8][160];    // 15.36 KB
    const int lane = threadIdx.x;   // 0..63
    const int mg   = lane >> 4;     // rows mg*8..+7
    const int ng   = lane & 15;     // cols ng*10..+9
    const int q    = blockIdx.x & 31;
    const int d    = blockIdx.x >> 5;   // 0..199

    const float* Qb = QpT + (size_t)q * (DIM_ * M_);
    const float* Db = DpT + (size_t)d * (DIM_ * N_);
    const float* gq = gum + ((size_t)q * ND_ + d) * ((size_t)M_ * N_);

    // ---- earliest loads: gumbel rows 0,1 / dmask / qmask
    float g[2][10];
#pragma unroll
    for (int r = 0; r < 2; ++r) {
        const float2* gp = reinterpret_cast<const float2*>(&gq[(size_t)(mg*8 + r) * N_ + ng*10]);
#pragma unroll
        for (int j2 = 0; j2 < 5; ++j2)
            *reinterpret_cast<float2*>(&g[r][j2*2]) = gp[j2];
    }
    float dmv[10];
    {
        const float* dmp = dmask + (size_t)d * N_ + ng * 10;
#pragma unroll
        for (int j2 = 0; j2 < 5; ++j2)
            *reinterpret_cast<float2*>(&dmv[j2*2]) = *reinterpret_cast<const float2*>(&dmp[j2*2]);
    }
    float qmv[8];
#pragma unroll
    for (int i = 0; i < 8; ++i) qmv[i] = qmask[q * M_ + mg*8 + i];

    float acc[8][10];
#pragma unroll
    for (int i = 0; i < 8; ++i)
#pragma unroll
        for (int j = 0; j < 10; ++j) acc[i][j] = 0.0f;

    // ---- staging helper: 6 gl_lds per chunk
#define ISSUE_CHUNK(c_)                                                     \
    do {                                                                    \
        const int b_ = (c_) % 3;                                            \
        const float* qs_ = Qb + (size_t)(c_) * 8 * M_;                      \
        const float* ds_ = Db + (size_t)(c_) * 8 * N_;                      \
        float* qd_ = &Qt[b_][0][0];                                         \
        float* dd_ = &Dt[b_][0][0];                                         \
        gl_lds16(qs_ + lane * 4, qd_);                                      \
        gl_lds16(ds_ + 0   + lane * 4, dd_ + 0);                            \
        gl_lds16(ds_ + 256 + lane * 4, dd_ + 256);                          \
        gl_lds16(ds_ + 512 + lane * 4, dd_ + 512);                          \
        gl_lds16(ds_ + 768 + lane * 4, dd_ + 768);                          \
        gl_lds16(ds_ + 1024 + lane * 4, dd_ + 1024);                        \
    } while (0)

    ISSUE_CHUNK(0);
    ISSUE_CHUNK(1);

    for (int c = 0; c < 16; ++c) {
        if (c < 15) { ASM_VMCNT(6); }   // chunk c done; chunk c+1 in flight
        else        { ASM_VMCNT(0); }
        if (c < 14) ISSUE_CHUNK(c + 2);
        __builtin_amdgcn_sched_barrier(0);
        const int cb = c % 3;
        const float* qtb = &Qt[cb][0][0];
        const float* dtb = &Dt[cb][0][0];
#pragma unroll
        for (int k = 0; k < 8; ++k) {
            float a[8], b[10];
            *reinterpret_cast<float4*>(&a[0]) = *reinterpret_cast<const float4*>(qtb + k*32 + mg*8);
            *reinterpret_cast<float4*>(&a[4]) = *reinterpret_cast<const float4*>(qtb + k*32 + mg*8 + 4);
            const float* bp = dtb + k*160 + ng*10;    // conflict-free b64s
#pragma unroll
            for (int j2 = 0; j2 < 5; ++j2)
                *reinterpret_cast<float2*>(&b[j2*2]) = *reinterpret_cast<const float2*>(&bp[j2*2]);
#pragma unroll
            for (int i = 0; i < 8; ++i)
#pragma unroll
                for (int j = 0; j < 10; ++j)
                    acc[i][j] = fmaf(a[i], b[j], acc[i][j]);
        }
    }
#undef ISSUE_CHUNK

    float partial = 0.0f;
#pragma unroll
    for (int i = 0; i < 8; ++i) {
        const int m = mg*8 + i;
        float x[10];
        float mx = -3.402823466e38f;
#pragma unroll
        for (int j = 0; j < 10; ++j) {
            float sm = (dmv[j] != 0.0f) ? acc[i][j] : -10000.0f;
            x[j] = sm / 0.1f;                 // IEEE divide: bit-matches np
            mx = fmaxf(mx, x[j]);
        }
        mx = fmaxf(mx, __shfl_xor(mx, 1));
        mx = fmaxf(mx, __shfl_xor(mx, 2));
        mx = fmaxf(mx, __shfl_xor(mx, 4));
        mx = fmaxf(mx, __shfl_xor(mx, 8));

        float se = 0.0f;
#pragma unroll
        for (int j = 0; j < 10; ++j) se = __fadd_rn(se, expf(x[j] - mx));
        se = __fadd_rn(se, __shfl_xor(se, 1));
        se = __fadd_rn(se, __shfl_xor(se, 2));
        se = __fadd_rn(se, __shfl_xor(se, 4));
        se = __fadd_rn(se, __shfl_xor(se, 8));
        const float lse = logf(se);

        float z[10];
        float mz = -3.402823466e38f;
#pragma unroll
        for (int j = 0; j < 10; ++j) {
            z[j] = ((x[j] - mx - lse) + g[i & 1][j]) / 0.5f;
            mz = fmaxf(mz, z[j]);
        }
        // refill this gumbel slot with row i+2 (consumed; 2-row lookahead)
        if (i < 6) {
            const float2* gp = reinterpret_cast<const float2*>(&gq[(size_t)(m + 2) * N_ + ng*10]);
#pragma unroll
            for (int j2 = 0; j2 < 5; ++j2)
                *reinterpret_cast<float2*>(&g[i & 1][j2*2]) = gp[j2];
        }
        mz = fmaxf(mz, __shfl_xor(mz, 1));
        mz = fmaxf(mz, __shfl_xor(mz, 2));
        mz = fmaxf(mz, __shfl_xor(mz, 4));
        mz = fmaxf(mz, __shfl_xor(mz, 8));

        float e2[10];
        float s2 = 0.0f;
#pragma unroll
        for (int j = 0; j < 10; ++j) { e2[j] = expf(z[j] - mz); s2 = __fadd_rn(s2, e2[j]); }
        s2 = __fadd_rn(s2, __shfl_xor(s2, 1));
        s2 = __fadd_rn(s2, __shfl_xor(s2, 2));
        s2 = __fadd_rn(s2, __shfl_xor(s2, 4));
        s2 = __fadd_rn(s2, __shfl_xor(s2, 8));

        // argmax of y_soft = e2/s2 with numpy first-index tie-break
        float besty = -1.0f; int bestn = 0x7fffffff; float bests = 0.0f;
#pragma unroll
        for (int j = 0; j < 10; ++j) {
            float y = e2[j] / s2;
            if (y > besty) {
                besty = y;
                bestn = ng*10 + j;
                bests = (dmv[j] != 0.0f) ? acc[i][j] : -10000.0f;
            }
        }
#pragma unroll
        for (int dl = 1; dl < 16; dl <<= 1) {
            float oy = __shfl_xor(besty, dl);
            int   on = __shfl_xor(bestn, dl);
            float os = __shfl_xor(bests, dl);
            if (oy > besty || (oy == besty && on < bestn)) {
                besty = oy; bestn = on; bests = os;
            }
        }
        if (ng == 0) partial = __fadd_rn(partial, __fmul_rn(bests, qmv[i]));
    }
    // ((m0..7 + m8..15) + (m16..23 + m24..31)) == numpy pairwise order
    partial = __fadd_rn(partial, __shfl_xor(partial, 16));
    partial = __fadd_rn(partial, __shfl_xor(partial, 32));
    if (lane == 0) out[(size_t)q * ND_ + d] = partial;
}

// ---------------------------------------------------------------------------
extern "C" void kernel_launch(void* const* d_in, const int* in_sizes, int n_in,
                              void* d_out, int out_size, void* d_ws, size_t ws_size,
                              hipStream_t stream)
{
    const float* Q   = (const float*)d_in[0];   // (32,32,768)
    const float* D   = (const float*)d_in[1];   // (200,160,768)
    const float* qm  = (const float*)d_in[2];   // (32,32)
    const float* dm  = (const float*)d_in[3];   // (200,160)
    const float* gum = (const float*)d_in[4];   // (32,200,32,160)
    const float* W   = (const float*)d_in[5];   // (768,128)
    float* out = (float*)d_out;                 // (32,200)

    float* QpT = (float*)d_ws;                          // 32*128*32   = 131072 floats
    float* DpT = QpT + (size_t)QROWS_ * DIM_;           // 200*128*160 = 4.096M floats

    proj_kernel<<<dim3(TROWS_ / 32), dim3(128), 0, stream>>>(D, Q, W, DpT, QpT);
    score_kernel<<<dim3(NQ_ * ND_), dim3(64), 0, stream>>>(QpT, DpT, qm, dm, gum, out);
}

// Round 4
// 517.262 us; speedup vs baseline: 1.2553x; 1.2553x over previous
//
#include <hip/hip_runtime.h>
#include <math.h>

#define NQ_   32
#define M_    32
#define ND_   200
#define N_    160
#define H_    768
#define DIM_  128
#define DROWS_ (ND_ * N_)          // 32000
#define QROWS_ (NQ_ * M_)          // 1024
#define TROWS_ (DROWS_ + QROWS_)   // 33024

// async global->LDS, 16B per lane: LDS dest = wave-uniform base + lane*16
__device__ __forceinline__ void gl_lds16(const float* g, float* l) {
    __builtin_amdgcn_global_load_lds(
        (const __attribute__((address_space(1))) unsigned int*)g,
        (__attribute__((address_space(3))) unsigned int*)l, 16, 0, 0);
}

// ---------------------------------------------------------------------------
// Merged projection — occupancy-first version.
// Rows 0..31999 = D, 32000..33023 = Q. Tile 16 rows x 128 cols, 128 threads
// (2 waves), per-thread 2x8, K-chunk 16, grid 2064 (= 8.06 blocks/CU).
// LDS 9.25 KB single-buffered -> 7-16 blocks/CU resident; latency is hidden
// by cross-block TLP (out-of-phase blocks), not intra-block pipelining.
//   staging per chunk: wave0 = X (64 lanes x float4 -> ds_write transposed),
//                      wave1 = W via 8 global_load_lds (2048 contiguous floats).
// Per-output-element FMA order (k ascending, chunks ascending) and the
// normalize/store values are bit-identical to all prior rounds.
// ---------------------------------------------------------------------------
__global__ __launch_bounds__(128) void proj_kernel(
    const float* __restrict__ Dmat, const float* __restrict__ Qmat,
    const float* __restrict__ W, float* __restrict__ DpT,
    float* __restrict__ QpT)
{
    __shared__ __align__(16) float Xt[16][16];     // [k][row], 1 KB
    __shared__ __align__(16) float Ws[16][128];    // [k][col], 8 KB
    const int tid  = threadIdx.x;
    const int lane = tid & 63;
    const int wv   = tid >> 6;
    const int rb   = blockIdx.x * 16;
    const int cg   = tid & 15;       // col group: cols cg*8..+7
    const int rg   = tid >> 4;       // row group 0..7: rows rg*2..+1
    const int xrow = lane >> 2;      // staging row 0..15 (wave0 only)
    const int xc4  = lane & 3;       // staging k-quad   (wave0 only)

    // wave0 staging source row (16-row blocks never straddle the D/Q split:
    // 32000 % 16 == 0)
    const int rX = rb + xrow;
    const float* xr_ptr = (rX < DROWS_) ? (Dmat + (size_t)rX * H_)
                                        : (Qmat + (size_t)(rX - DROWS_) * H_);

    float acc[2][8];
#pragma unroll
    for (int i = 0; i < 2; ++i)
#pragma unroll
        for (int j = 0; j < 8; ++j) acc[i][j] = 0.0f;

    for (int kc = 0; kc < H_; kc += 16) {
        if (wv == 0) {
            // X chunk: 16 rows x 16 k = 64 float4, one per lane
            float4 v = *reinterpret_cast<const float4*>(xr_ptr + kc + xc4 * 4);
            Xt[xc4*4+0][xrow] = v.x;
            Xt[xc4*4+1][xrow] = v.y;
            Xt[xc4*4+2][xrow] = v.z;
            Xt[xc4*4+3][xrow] = v.w;
        } else {
            // W chunk: 16 k x 128 cols = 2048 contiguous floats = 8 gl_lds
            const float* wsrc = W + (size_t)kc * DIM_;
#pragma unroll
            for (int t = 0; t < 8; ++t)
                gl_lds16(wsrc + t * 256 + lane * 4, &Ws[0][0] + t * 256);
        }
        __syncthreads();            // drains vmcnt+lgkm -> LDS visible
#pragma unroll
        for (int k = 0; k < 16; ++k) {
            float a[2], b[8];
            *reinterpret_cast<float2*>(&a[0]) = *reinterpret_cast<const float2*>(&Xt[k][rg*2]);
            *reinterpret_cast<float4*>(&b[0]) = *reinterpret_cast<const float4*>(&Ws[k][cg*8]);
            *reinterpret_cast<float4*>(&b[4]) = *reinterpret_cast<const float4*>(&Ws[k][cg*8+4]);
#pragma unroll
            for (int i = 0; i < 2; ++i)
#pragma unroll
                for (int j = 0; j < 8; ++j)
                    acc[i][j] = fmaf(a[i], b[j], acc[i][j]);
        }
        __syncthreads();
    }

    // L2 norms: row r's 128 cols live in the 16 same-rg lanes (a contiguous
    // 16-lane group of one wave). Same reduce order as all prior rounds.
    float nrm[2];
#pragma unroll
    for (int i = 0; i < 2; ++i) {
        float ss = 0.0f;
#pragma unroll
        for (int j = 0; j < 8; ++j) ss = __fadd_rn(ss, __fmul_rn(acc[i][j], acc[i][j]));
        ss = __fadd_rn(ss, __shfl_xor(ss, 1));
        ss = __fadd_rn(ss, __shfl_xor(ss, 2));
        ss = __fadd_rn(ss, __shfl_xor(ss, 4));
        ss = __fadd_rn(ss, __shfl_xor(ss, 8));
        nrm[i] = fmaxf(sqrtf(ss), 1e-12f);
    }

    if (rb < DROWS_) {
        const int dd = rb / 160, n0 = rb - dd * 160;   // 16-row blocks stay within one d
        float* o = DpT + (size_t)dd * (DIM_ * N_) + n0 + rg * 2;
#pragma unroll
        for (int j = 0; j < 8; ++j) {
            float2 v;
            v.x = acc[0][j] / nrm[0];
            v.y = acc[1][j] / nrm[1];
            *reinterpret_cast<float2*>(o + (size_t)(cg*8 + j) * N_) = v;
        }
    } else {
        const int rq = rb - DROWS_;
        const int qq = rq >> 5, m0 = rq & 31;          // m0 in {0,16}
        float* o = QpT + (size_t)qq * (DIM_ * M_) + m0 + rg * 2;
#pragma unroll
        for (int j = 0; j < 8; ++j) {
            float2 v;
            v.x = acc[0][j] / nrm[0];
            v.y = acc[1][j] / nrm[1];
            *reinterpret_cast<float2*>(o + (size_t)(cg*8 + j) * M_) = v;
        }
    }
}

// ---------------------------------------------------------------------------
// Score: one wave per (q,d). grid 6400 (q fast for DpT L2 reuse). K-chunk 8,
// LDS 6 KB/block -> high occupancy. Staging via global_load_lds (contiguous
// k-major chunks, no transpose, no ds_writes). Lane tile 8 rows x 10 cols.
// [VERBATIM round-0 kernel — measured 198 us, VALUBusy 65%, occ 25%.]
// ---------------------------------------------------------------------------
__global__ __launch_bounds__(64) void score_kernel(
    const float* __restrict__ QpT, const float* __restrict__ DpT,
    const float* __restrict__ qmask, const float* __restrict__ dmask,
    const float* __restrict__ gum, float* __restrict__ out)
{
    __shared__ float Qt[8][32];     // [k][m]
    __shared__ float Dt[8][160];    // [k][n]
    const int lane = threadIdx.x;   // 0..63
    const int mg   = lane >> 4;     // rows mg*8..+7
    const int ng   = lane & 15;     // cols ng*10..+9
    const int q    = blockIdx.x & 31;
    const int d    = blockIdx.x >> 5;   // 0..199

    const float* Qb = QpT + (size_t)q * (DIM_ * M_);
    const float* Db = DpT + (size_t)d * (DIM_ * N_);

    float acc[8][10];
#pragma unroll
    for (int i = 0; i < 8; ++i)
#pragma unroll
        for (int j = 0; j < 10; ++j) acc[i][j] = 0.0f;

    for (int kc = 0; kc < DIM_; kc += 8) {
        // Qt chunk: 8x32 = 256 floats = 64 lanes x 16B, one call
        gl_lds16(Qb + kc * M_ + lane * 4, &Qt[0][0]);
        // Dt chunk: 8x160 = 1280 floats, 5 calls
#pragma unroll
        for (int c = 0; c < 5; ++c)
            gl_lds16(Db + kc * N_ + c * 256 + lane * 4, &Dt[0][0] + c * 256);
        __syncthreads();            // drains vmcnt -> LDS visible
#pragma unroll
        for (int k = 0; k < 8; ++k) {
            float a[8], b[10];
            *reinterpret_cast<float4*>(&a[0]) = *reinterpret_cast<const float4*>(&Qt[k][mg*8]);
            *reinterpret_cast<float4*>(&a[4]) = *reinterpret_cast<const float4*>(&Qt[k][mg*8+4]);
            const float* bp = &Dt[k][ng*10];    // 8B aligned, conflict-free banks
#pragma unroll
            for (int j2 = 0; j2 < 5; ++j2)
                *reinterpret_cast<float2*>(&b[j2*2]) = *reinterpret_cast<const float2*>(&bp[j2*2]);
#pragma unroll
            for (int i = 0; i < 8; ++i)
#pragma unroll
                for (int j = 0; j < 10; ++j)
                    acc[i][j] = fmaf(a[i], b[j], acc[i][j]);
        }
        __syncthreads();
    }

    float dmv[10];
#pragma unroll
    for (int j = 0; j < 10; ++j)
        dmv[j] = dmask[(size_t)d * N_ + ng*10 + j];

    const float* gq = gum + ((size_t)q * ND_ + d) * ((size_t)M_ * N_);

    float partial = 0.0f;
#pragma unroll
    for (int i = 0; i < 8; ++i) {
        const int m = mg*8 + i;
        float x[10];
        float mx = -3.402823466e38f;
#pragma unroll
        for (int j = 0; j < 10; ++j) {
            float sm = (dmv[j] != 0.0f) ? acc[i][j] : -10000.0f;
            x[j] = sm / 0.1f;                 // IEEE divide: bit-matches np
            mx = fmaxf(mx, x[j]);
        }
        mx = fmaxf(mx, __shfl_xor(mx, 1));
        mx = fmaxf(mx, __shfl_xor(mx, 2));
        mx = fmaxf(mx, __shfl_xor(mx, 4));
        mx = fmaxf(mx, __shfl_xor(mx, 8));

        float se = 0.0f;
#pragma unroll
        for (int j = 0; j < 10; ++j) se = __fadd_rn(se, expf(x[j] - mx));
        se = __fadd_rn(se, __shfl_xor(se, 1));
        se = __fadd_rn(se, __shfl_xor(se, 2));
        se = __fadd_rn(se, __shfl_xor(se, 4));
        se = __fadd_rn(se, __shfl_xor(se, 8));
        const float lse = logf(se);

        float g[10];
        const float2* gp = reinterpret_cast<const float2*>(&gq[(size_t)m * N_ + ng*10]);
#pragma unroll
        for (int j2 = 0; j2 < 5; ++j2)
            *reinterpret_cast<float2*>(&g[j2*2]) = gp[j2];

        float z[10];
        float mz = -3.402823466e38f;
#pragma unroll
        for (int j = 0; j < 10; ++j) {
            z[j] = ((x[j] - mx - lse) + g[j]) / 0.5f;
            mz = fmaxf(mz, z[j]);
        }
        mz = fmaxf(mz, __shfl_xor(mz, 1));
        mz = fmaxf(mz, __shfl_xor(mz, 2));
        mz = fmaxf(mz, __shfl_xor(mz, 4));
        mz = fmaxf(mz, __shfl_xor(mz, 8));

        float e2[10];
        float s2 = 0.0f;
#pragma unroll
        for (int j = 0; j < 10; ++j) { e2[j] = expf(z[j] - mz); s2 = __fadd_rn(s2, e2[j]); }
        s2 = __fadd_rn(s2, __shfl_xor(s2, 1));
        s2 = __fadd_rn(s2, __shfl_xor(s2, 2));
        s2 = __fadd_rn(s2, __shfl_xor(s2, 4));
        s2 = __fadd_rn(s2, __shfl_xor(s2, 8));

        // argmax of y_soft = e2/s2 with numpy first-index tie-break
        float besty = -1.0f; int bestn = 0x7fffffff; float bests = 0.0f;
#pragma unroll
        for (int j = 0; j < 10; ++j) {
            float y = e2[j] / s2;
            if (y > besty) {
                besty = y;
                bestn = ng*10 + j;
                bests = (dmv[j] != 0.0f) ? acc[i][j] : -10000.0f;
            }
        }
#pragma unroll
        for (int dl = 1; dl < 16; dl <<= 1) {
            float oy = __shfl_xor(besty, dl);
            int   on = __shfl_xor(bestn, dl);
            float os = __shfl_xor(bests, dl);
            if (oy > besty || (oy == besty && on < bestn)) {
                besty = oy; bestn = on; bests = os;
            }
        }
        const float qmv = qmask[q * M_ + m];
        if (ng == 0) partial = __fadd_rn(partial, __fmul_rn(bests, qmv));
    }
    // ((m0..7 + m8..15) + (m16..23 + m24..31)) == numpy pairwise order
    partial = __fadd_rn(partial, __shfl_xor(partial, 16));
    partial = __fadd_rn(partial, __shfl_xor(partial, 32));
    if (lane == 0) out[(size_t)q * ND_ + d] = partial;
}

// ---------------------------------------------------------------------------
extern "C" void kernel_launch(void* const* d_in, const int* in_sizes, int n_in,
                              void* d_out, int out_size, void* d_ws, size_t ws_size,
                              hipStream_t stream)
{
    const float* Q   = (const float*)d_in[0];   // (32,32,768)
    const float* D   = (const float*)d_in[1];   // (200,160,768)
    const float* qm  = (const float*)d_in[2];   // (32,32)
    const float* dm  = (const float*)d_in[3];   // (200,160)
    const float* gum = (const float*)d_in[4];   // (32,200,32,160)
    const float* W   = (const float*)d_in[5];   // (768,128)
    float* out = (float*)d_out;                 // (32,200)

    float* QpT = (float*)d_ws;                          // 32*128*32   = 131072 floats
    float* DpT = QpT + (size_t)QROWS_ * DIM_;           // 200*128*160 = 4.096M floats

    proj_kernel<<<dim3(TROWS_ / 16), dim3(128), 0, stream>>>(D, Q, W, DpT, QpT);
    score_kernel<<<dim3(NQ_ * ND_), dim3(64), 0, stream>>>(QpT, DpT, qm, dm, gum, out);
}